// Round 2
// baseline (550.783 us; speedup 1.0000x reference)
//
#include <hip/hip_runtime.h>

typedef unsigned int u32;
typedef unsigned short u16;
typedef __attribute__((ext_vector_type(8))) short short8;
typedef __attribute__((ext_vector_type(4))) float f32x4;

__device__ __forceinline__ float bf2f(u16 u) {
  union { u32 i; float f; } v; v.i = ((u32)u) << 16; return v.f;
}
__device__ __forceinline__ u16 f2bf(float f) {
  union { float f; u32 i; } v; v.f = f;
  u32 u = v.i;
  u += 0x7FFFu + ((u >> 16) & 1u);
  return (u16)(u >> 16);
}
__device__ __forceinline__ float tanh_fast(float x) {
  float e = __expf(-2.f * fabsf(x));
  float r = (1.f - e) / (1.f + e);
  return x < 0.f ? -r : r;
}
__device__ __forceinline__ float sigmoid_fast(float x) {
  return 1.f / (1.f + __expf(-x));
}

// ---- dtype-generic IO helpers (F32: inputs/outputs are float32) ----
template<bool F32>
__device__ __forceinline__ float ld1(const void* p, size_t i) {
  return F32 ? ((const float*)p)[i] : bf2f(((const u16*)p)[i]);
}
template<bool F32>
__device__ __forceinline__ void ld8(const void* p, size_t i, float* o) {
  if (F32) {
    float4 a = *(const float4*)((const float*)p + i);
    float4 b = *(const float4*)((const float*)p + i + 4);
    o[0]=a.x; o[1]=a.y; o[2]=a.z; o[3]=a.w; o[4]=b.x; o[5]=b.y; o[6]=b.z; o[7]=b.w;
  } else {
    short8 v = *(const short8*)((const u16*)p + i);
    #pragma unroll
    for (int j = 0; j < 8; j++) o[j] = bf2f((u16)v[j]);
  }
}
template<bool F32>
__device__ __forceinline__ short8 ldfrag8(const void* p, size_t i) {
  if (!F32) return *(const short8*)((const u16*)p + i);
  float4 a = *(const float4*)((const float*)p + i);
  float4 b = *(const float4*)((const float*)p + i + 4);
  short8 r;
  r[0]=(short)f2bf(a.x); r[1]=(short)f2bf(a.y); r[2]=(short)f2bf(a.z); r[3]=(short)f2bf(a.w);
  r[4]=(short)f2bf(b.x); r[5]=(short)f2bf(b.y); r[6]=(short)f2bf(b.z); r[7]=(short)f2bf(b.w);
  return r;
}
template<bool F32>
__device__ __forceinline__ void st1(void* p, size_t i, float v) {
  if (F32) ((float*)p)[i] = v; else ((u16*)p)[i] = f2bf(v);
}

// element offsets into d_out (dtype-independent)
#define OFF_LOGITS 0
#define OFF_H      2048000
#define OFF_C      2113536
#define OFF_ATTN   2179072

// ---------------------------------------------------------------------------
// K0: dtype probe. ln_emb_g == 1.0...: f32 -> 0x3F800000, bf16 -> 0x3F803F80
// ---------------------------------------------------------------------------
__global__ void k_flag(const u32* __restrict__ lneg, int* __restrict__ flag) {
  if (threadIdx.x == 0) flag[0] = (lneg[0] == 0x3F800000u) ? 1 : 0;
}

// ---------------------------------------------------------------------------
// K1: embedding+LN -> xcat[:,0:512]; h0[0] -> xcat[:,1536:2048];
//     dec_proj(+b_dec+b_enc) -> dp; h0[1] -> xcat1[:,512:1024]
// ---------------------------------------------------------------------------
template<bool F32>
__global__ __launch_bounds__(256) void k_prep(
    const int* __restrict__ flag,
    const int* __restrict__ tok, const void* __restrict__ h0,
    const void* __restrict__ emb,
    const void* __restrict__ lng, const void* __restrict__ lnb,
    const void* __restrict__ benc,
    const void* __restrict__ Wdec, const void* __restrict__ bdec,
    u16* __restrict__ xcat, u16* __restrict__ xcat1,
    float* __restrict__ dp)
{
  if (flag[0] != (F32 ? 1 : 0)) return;
  __shared__ float red[8];
  __shared__ float hl[512];
  const int t = threadIdx.x;
  const int blk = blockIdx.x;
  if (blk < 64) {
    const int b = blk;
    const int tk = tok[b];
    float e0 = ld1<F32>(emb, (size_t)tk * 512 + t);
    float e1 = ld1<F32>(emb, (size_t)tk * 512 + t + 256);
    float s = e0 + e1, ss = e0 * e0 + e1 * e1;
    #pragma unroll
    for (int o = 1; o < 64; o <<= 1) { s += __shfl_xor(s, o, 64); ss += __shfl_xor(ss, o, 64); }
    if ((t & 63) == 0) { red[t >> 6] = s; red[4 + (t >> 6)] = ss; }
    __syncthreads();
    s = red[0] + red[1] + red[2] + red[3];
    ss = red[4] + red[5] + red[6] + red[7];
    const float mean = s * (1.f / 512.f);
    const float rstd = rsqrtf(fmaxf(ss * (1.f / 512.f) - mean * mean, 0.f) + 1e-5f);
    xcat[b * 2048 + t]       = f2bf((e0 - mean) * rstd * ld1<F32>(lng, t) + ld1<F32>(lnb, t));
    xcat[b * 2048 + t + 256] = f2bf((e1 - mean) * rstd * ld1<F32>(lng, t + 256) + ld1<F32>(lnb, t + 256));
    xcat[b * 2048 + 1536 + t]       = f2bf(ld1<F32>(h0, (size_t)b * 512 + t));
    xcat[b * 2048 + 1536 + t + 256] = f2bf(ld1<F32>(h0, (size_t)b * 512 + t + 256));
  } else {
    const int b = blk - 64;
    float h1a = ld1<F32>(h0, 32768 + (size_t)b * 512 + t);
    float h1b = ld1<F32>(h0, 32768 + (size_t)b * 512 + t + 256);
    hl[t] = h1a; hl[t + 256] = h1b;
    xcat1[b * 1024 + 512 + t]       = f2bf(h1a);
    xcat1[b * 1024 + 512 + t + 256] = f2bf(h1b);
    __syncthreads();
    for (int aa = t; aa < 512; aa += 256) {
      float acc = ld1<F32>(bdec, aa) + ld1<F32>(benc, aa);
      #pragma unroll 4
      for (int k = 0; k < 512; k += 8) {
        float w8[8];
        ld8<F32>(Wdec, (size_t)aa * 512 + k, w8);
        #pragma unroll
        for (int i = 0; i < 8; i++) acc += hl[k + i] * w8[i];
      }
      dp[b * 512 + aa] = acc;
    }
  }
}

// ---------------------------------------------------------------------------
// K2: fused scores GEMM: combined = enc@Wenc^T + dp ; LN ; tanh ; dot v_att
// ---------------------------------------------------------------------------
template<bool F32>
__global__ __launch_bounds__(512) void k_scores(
    const int* __restrict__ flag,
    const void* __restrict__ enc, const void* __restrict__ Wenc,
    const float* __restrict__ dp,
    const void* __restrict__ lng, const void* __restrict__ lnb,
    const void* __restrict__ vat, const int* __restrict__ mask,
    float* __restrict__ scores)
{
  if (flag[0] != (F32 ? 1 : 0)) return;
  __shared__ __align__(16) char sm[65536];
  const int t = threadIdx.x;
  const int wave = t >> 6, lane = t & 63;
  const int q = lane >> 4, r15 = lane & 15;
  const int m0 = blockIdx.x * 64;
  const int b = m0 >> 8;
  const int n0 = wave * 64;

  f32x4 acc[4][4] = {};

  for (int kc = 0; kc < 1024; kc += 32) {
    #pragma unroll
    for (int rr = 0; rr < 5; ++rr) {
      int c = rr * 512 + t;
      if (c < 2304) {
        short8 v; char* dst;
        if (c < 256) {
          int cq = c >> 6, row = c & 63;
          v = ldfrag8<F32>(enc, (size_t)(m0 + row) * 1024 + kc + cq * 8);
          dst = sm + c * 16;
        } else {
          int c2 = c - 256;
          int cq = c2 >> 9, col = c2 & 511;
          v = ldfrag8<F32>(Wenc, (size_t)col * 1024 + kc + cq * 8);
          dst = sm + 4096 + c2 * 16;
        }
        *(short8*)dst = v;
      }
    }
    __syncthreads();
    short8 af[4], bfr[4];
    #pragma unroll
    for (int mi = 0; mi < 4; mi++)
      af[mi] = *(const short8*)(sm + (q * 64 + mi * 16 + r15) * 16);
    #pragma unroll
    for (int ni = 0; ni < 4; ni++)
      bfr[ni] = *(const short8*)(sm + 4096 + (q * 512 + n0 + ni * 16 + r15) * 16);
    #pragma unroll
    for (int mi = 0; mi < 4; mi++)
      #pragma unroll
      for (int ni = 0; ni < 4; ni++)
        acc[mi][ni] = __builtin_amdgcn_mfma_f32_16x16x32_bf16(af[mi], bfr[ni], acc[mi][ni], 0, 0, 0);
    __syncthreads();
  }

  float dpv[4];
  #pragma unroll
  for (int ni = 0; ni < 4; ni++) dpv[ni] = dp[b * 512 + n0 + ni * 16 + r15];
  u16* res = (u16*)sm;  // [64][512]
  #pragma unroll
  for (int mi = 0; mi < 4; mi++)
    #pragma unroll
    for (int ni = 0; ni < 4; ni++)
      #pragma unroll
      for (int r = 0; r < 4; r++) {
        int row = mi * 16 + q * 4 + r;
        int col = n0 + ni * 16 + r15;
        res[row * 512 + col] = f2bf(acc[mi][ni][r] + dpv[ni]);
      }
  __syncthreads();

  const int row = t >> 3, part = t & 7;
  float sum = 0.f, ssum = 0.f;
  #pragma unroll
  for (int j = 0; j < 8; j++) {
    int cb = part * 8 + j * 64;
    short8 xv = *(const short8*)(res + row * 512 + cb);
    #pragma unroll
    for (int i = 0; i < 8; i++) { float x = bf2f((u16)xv[i]); sum += x; ssum += x * x; }
  }
  #pragma unroll
  for (int o = 1; o < 8; o <<= 1) { sum += __shfl_xor(sum, o, 64); ssum += __shfl_xor(ssum, o, 64); }
  const float mean = sum * (1.f / 512.f);
  const float rstd = rsqrtf(fmaxf(ssum * (1.f / 512.f) - mean * mean, 0.f) + 1e-5f);
  float sc = 0.f;
  #pragma unroll
  for (int j = 0; j < 8; j++) {
    int cb = part * 8 + j * 64;
    short8 xv = *(const short8*)(res + row * 512 + cb);
    float g8[8], b8[8], v8[8];
    ld8<F32>(lng, cb, g8); ld8<F32>(lnb, cb, b8); ld8<F32>(vat, cb, v8);
    #pragma unroll
    for (int i = 0; i < 8; i++) {
      float x = (bf2f((u16)xv[i]) - mean) * rstd * g8[i] + b8[i];
      sc += tanh_fast(x) * v8[i];
    }
  }
  #pragma unroll
  for (int o = 1; o < 8; o <<= 1) sc += __shfl_xor(sc, o, 64);
  if (part == 0) {
    int m = m0 + row;
    int s = (m0 & 255) + row;
    scores[m] = mask[b * 256 + s] ? sc : -__builtin_inff();
  }
}

// ---------------------------------------------------------------------------
// K3: softmax over S + context slice
// ---------------------------------------------------------------------------
template<bool F32>
__global__ __launch_bounds__(256) void k_softmax_ctx(
    const int* __restrict__ flag,
    const float* __restrict__ scores, const void* __restrict__ enc,
    u16* __restrict__ xcat, void* __restrict__ out)
{
  if (flag[0] != (F32 ? 1 : 0)) return;
  __shared__ float aw[256];
  __shared__ float red[8];
  const int t = threadIdx.x;
  const int b = blockIdx.x >> 2, kq = blockIdx.x & 3;
  float sv = scores[b * 256 + t];
  float mx = sv;
  #pragma unroll
  for (int o = 1; o < 64; o <<= 1) mx = fmaxf(mx, __shfl_xor(mx, o, 64));
  if ((t & 63) == 0) red[t >> 6] = mx;
  __syncthreads();
  mx = fmaxf(fmaxf(red[0], red[1]), fmaxf(red[2], red[3]));
  float e = __expf(sv - mx);
  float s = e;
  #pragma unroll
  for (int o = 1; o < 64; o <<= 1) s += __shfl_xor(s, o, 64);
  if ((t & 63) == 0) red[4 + (t >> 6)] = s;
  __syncthreads();
  s = red[4] + red[5] + red[6] + red[7];
  float w = e / s;
  aw[t] = w;
  if (kq == 0) st1<F32>(out, OFF_ATTN + b * 256 + t, w);
  __syncthreads();
  const int k = kq * 256 + t;
  float acc = 0.f;
  #pragma unroll 8
  for (int sidx = 0; sidx < 256; sidx++)
    acc += aw[sidx] * ld1<F32>(enc, (size_t)b * 262144 + (size_t)sidx * 1024 + k);
  xcat[b * 2048 + 512 + k] = f2bf(acc);
}

// ---------------------------------------------------------------------------
// K4: LSTM layer: gates GEMM (M=64,N=2048, split-K over 8 waves) + fused cell
// ---------------------------------------------------------------------------
template<bool F32>
__global__ __launch_bounds__(512) void k_lstm(
    const int* __restrict__ flag,
    const u16* __restrict__ x, int K,
    const void* __restrict__ Wa, int Ka,
    const void* __restrict__ Wb, int Kb,
    const void* __restrict__ bih, const void* __restrict__ bhh,
    const void* __restrict__ cprev,
    void* __restrict__ out, size_t h_off, size_t c_off,
    u16* __restrict__ h_aux_bf, float* __restrict__ h_aux_f)
{
  if (flag[0] != (F32 ? 1 : 0)) return;
  __shared__ __align__(16) char sm[65536];
  const int t = threadIdx.x, wave = t >> 6, lane = t & 63;
  const int q = lane >> 4, r15 = lane & 15;
  const int jt = blockIdx.x;
  const int kslice = K >> 3;
  const int ksteps = kslice >> 5;
  const int k0 = wave * kslice;
  const void* W; int wstride, koff;
  if (k0 < Ka) { W = Wa; wstride = Ka; koff = k0; }
  else         { W = Wb; wstride = Kb; koff = k0 - Ka; }
  char* slab = sm + wave * 8192;
  const u16* As = (const u16*)slab;
  const u16* Bs = (const u16*)(slab + 4096);
  f32x4 acc[4][4] = {};

  for (int st = 0; st < ksteps; ++st) {
    const int kA = k0 + st * 32;
    const int kB = koff + st * 32;
    #pragma unroll
    for (int rr = 0; rr < 8; ++rr) {
      int c = rr * 64 + lane;
      if (c < 256) {
        int cq = c >> 6, row = c & 63;
        *(uint4*)(slab + c * 16) = *(const uint4*)(x + (size_t)row * K + kA + cq * 8);
      } else {
        int c2 = c - 256;
        int cq = c2 >> 6, rt = c2 & 63;
        int wrow = (rt >> 4) * 512 + jt * 16 + (rt & 15);
        short8 v = ldfrag8<F32>(W, (size_t)wrow * wstride + kB + cq * 8);
        *(short8*)(slab + 4096 + c2 * 16) = v;
      }
    }
    short8 af[4], bfr[4];
    #pragma unroll
    for (int mi = 0; mi < 4; mi++)
      af[mi] = *(const short8*)(As + (q * 64 + mi * 16 + r15) * 8);
    #pragma unroll
    for (int ni = 0; ni < 4; ni++)
      bfr[ni] = *(const short8*)(Bs + (q * 64 + ni * 16 + r15) * 8);
    #pragma unroll
    for (int mi = 0; mi < 4; mi++)
      #pragma unroll
      for (int ni = 0; ni < 4; ni++)
        acc[mi][ni] = __builtin_amdgcn_mfma_f32_16x16x32_bf16(af[mi], bfr[ni], acc[mi][ni], 0, 0, 0);
  }
  __syncthreads();
  float* reg0 = (float*)sm;
  if (wave < 4) {
    float* rg = (float*)(sm + wave * 16384);
    #pragma unroll
    for (int mi = 0; mi < 4; mi++)
      #pragma unroll
      for (int ni = 0; ni < 4; ni++)
        #pragma unroll
        for (int r = 0; r < 4; r++)
          rg[(mi * 16 + q * 4 + r) * 64 + ni * 16 + r15] = acc[mi][ni][r];
  }
  __syncthreads();
  if (wave >= 4) {
    float* rg = (float*)(sm + (wave - 4) * 16384);
    #pragma unroll
    for (int mi = 0; mi < 4; mi++)
      #pragma unroll
      for (int ni = 0; ni < 4; ni++)
        #pragma unroll
        for (int r = 0; r < 4; r++)
          rg[(mi * 16 + q * 4 + r) * 64 + ni * 16 + r15] += acc[mi][ni][r];
  }
  __syncthreads();
  {
    float* r1 = (float*)(sm + 16384);
    float* r2 = (float*)(sm + 32768);
    float* r3 = (float*)(sm + 49152);
    for (int i = t; i < 4096; i += 512) reg0[i] += r1[i] + r2[i] + r3[i];
  }
  __syncthreads();
  for (int cell = t; cell < 1024; cell += 512) {
    const int b = cell >> 4, jl = cell & 15;
    const int jg = jt * 16 + jl;
    float gi = reg0[b * 64 + jl]      + ld1<F32>(bih, jg)        + ld1<F32>(bhh, jg);
    float gf = reg0[b * 64 + 16 + jl] + ld1<F32>(bih, 512 + jg)  + ld1<F32>(bhh, 512 + jg);
    float gg = reg0[b * 64 + 32 + jl] + ld1<F32>(bih, 1024 + jg) + ld1<F32>(bhh, 1024 + jg);
    float go = reg0[b * 64 + 48 + jl] + ld1<F32>(bih, 1536 + jg) + ld1<F32>(bhh, 1536 + jg);
    float i_ = sigmoid_fast(gi), f_ = sigmoid_fast(gf), o_ = sigmoid_fast(go);
    float g_ = tanh_fast(gg);
    float c_ = f_ * ld1<F32>(cprev, b * 512 + jg) + i_ * g_;
    float h_ = o_ * tanh_fast(c_);
    st1<F32>(out, h_off + b * 512 + jg, h_);
    st1<F32>(out, c_off + b * 512 + jg, c_);
    if (h_aux_bf) h_aux_bf[b * 1024 + jg] = f2bf(h_);
    if (h_aux_f)  h_aux_f[b * 512 + jg] = h_;
  }
}

// ---------------------------------------------------------------------------
// K5: svec = LN(h_l1)*g+b + context@Wctx^T + b_ctx
// ---------------------------------------------------------------------------
template<bool F32>
__global__ __launch_bounds__(256) void k_svec(
    const int* __restrict__ flag,
    const float* __restrict__ hl1f, const u16* __restrict__ xcat,
    const void* __restrict__ Wctx, const void* __restrict__ bctx,
    const void* __restrict__ lng, const void* __restrict__ lnb,
    u16* __restrict__ svec)
{
  if (flag[0] != (F32 ? 1 : 0)) return;
  __shared__ float ctx[1024];
  __shared__ float red[8];
  const int t = threadIdx.x, b = blockIdx.x;
  for (int i = t; i < 1024; i += 256) ctx[i] = bf2f(xcat[b * 2048 + 512 + i]);
  float h0v = hl1f[b * 512 + t], h1v = hl1f[b * 512 + t + 256];
  float s = h0v + h1v, ss = h0v * h0v + h1v * h1v;
  #pragma unroll
  for (int o = 1; o < 64; o <<= 1) { s += __shfl_xor(s, o, 64); ss += __shfl_xor(ss, o, 64); }
  if ((t & 63) == 0) { red[t >> 6] = s; red[4 + (t >> 6)] = ss; }
  __syncthreads();
  s = red[0] + red[1] + red[2] + red[3];
  ss = red[4] + red[5] + red[6] + red[7];
  const float mean = s * (1.f / 512.f);
  const float rstd = rsqrtf(fmaxf(ss * (1.f / 512.f) - mean * mean, 0.f) + 1e-5f);
  for (int hh = t; hh < 512; hh += 256) {
    float hv = hl1f[b * 512 + hh];
    float lnv = (hv - mean) * rstd * ld1<F32>(lng, hh) + ld1<F32>(lnb, hh);
    float acc = ld1<F32>(bctx, hh);
    #pragma unroll 4
    for (int k = 0; k < 1024; k += 8) {
      float w8[8];
      ld8<F32>(Wctx, (size_t)hh * 1024 + k, w8);
      #pragma unroll
      for (int i = 0; i < 8; i++) acc += ctx[k + i] * w8[i];
    }
    svec[b * 512 + hh] = f2bf(lnv + acc);
  }
}

// ---------------------------------------------------------------------------
// K6: logits = svec @ Wout^T + b_out
// ---------------------------------------------------------------------------
template<bool F32>
__global__ __launch_bounds__(256) void k_logits(
    const int* __restrict__ flag,
    const u16* __restrict__ svec, const void* __restrict__ Wout,
    const void* __restrict__ bout, void* __restrict__ out)
{
  if (flag[0] != (F32 ? 1 : 0)) return;
  __shared__ __align__(16) char sm[65536];
  const int t = threadIdx.x, wave = t >> 6, lane = t & 63;
  const int q = lane >> 4, r15 = lane & 15;
  const int nb = blockIdx.x * 128;
  #pragma unroll
  for (int rr = 0; rr < 16; ++rr) {
    int c = rr * 256 + t;
    int kq = c >> 6, row = c & 63;
    *(uint4*)(sm + c * 16) = *(const uint4*)(svec + (size_t)row * 512 + kq * 8);
  }
  __syncthreads();
  const int n0 = nb + wave * 32;
  f32x4 acc[4][2] = {};
  #pragma unroll
  for (int kc = 0; kc < 16; ++kc) {
    short8 af[4], bfr[2];
    #pragma unroll
    for (int mi = 0; mi < 4; mi++)
      af[mi] = *(const short8*)((const u16*)sm + ((kc * 4 + q) * 64 + mi * 16 + r15) * 8);
    #pragma unroll
    for (int ni = 0; ni < 2; ni++)
      bfr[ni] = ldfrag8<F32>(Wout, (size_t)(n0 + ni * 16 + r15) * 512 + kc * 32 + q * 8);
    #pragma unroll
    for (int mi = 0; mi < 4; mi++)
      #pragma unroll
      for (int ni = 0; ni < 2; ni++)
        acc[mi][ni] = __builtin_amdgcn_mfma_f32_16x16x32_bf16(af[mi], bfr[ni], acc[mi][ni], 0, 0, 0);
  }
  #pragma unroll
  for (int ni = 0; ni < 2; ni++) {
    float bo = ld1<F32>(bout, n0 + ni * 16 + r15);
    #pragma unroll
    for (int mi = 0; mi < 4; mi++)
      #pragma unroll
      for (int r = 0; r < 4; r++) {
        int brow = mi * 16 + q * 4 + r;
        int col = n0 + ni * 16 + r15;
        st1<F32>(out, (size_t)brow * 32000 + col, acc[mi][ni][r] + bo);
      }
  }
}

// ---------------------------------------------------------------------------
extern "C" void kernel_launch(void* const* d_in, const int* in_sizes, int n_in,
                              void* d_out, int out_size, void* d_ws, size_t ws_size,
                              hipStream_t stream)
{
  const int* tok  = (const int*)d_in[0];
  const void* h0  = d_in[1];
  const void* c0v = d_in[2];
  const void* enc = d_in[3];
  const int* mask = (const int*)d_in[4];
  const void* emb = d_in[5];
  const void* lneg = d_in[6];
  const void* lneb = d_in[7];
  const void* Wenc = d_in[8];
  const void* benc = d_in[9];
  const void* Wdec = d_in[10];
  const void* bdec = d_in[11];
  const void* vat  = d_in[12];
  const void* lnag = d_in[13];
  const void* lnab = d_in[14];
  const void* Wih0 = d_in[15];
  const void* Whh0 = d_in[16];
  const void* bih0 = d_in[17];
  const void* bhh0 = d_in[18];
  const void* Wih1 = d_in[19];
  const void* Whh1 = d_in[20];
  const void* bih1 = d_in[21];
  const void* bhh1 = d_in[22];
  const void* lnlg = d_in[23];
  const void* lnlb = d_in[24];
  const void* Wctx = d_in[25];
  const void* bctx = d_in[26];
  const void* Wout = d_in[27];
  const void* bout = d_in[28];

  char* ws = (char*)d_ws;
  int*  flag   = (int*)(ws + 0);             // 256 B reserved
  u16*  xcat   = (u16*)(ws + 256);           // [64][2048] bf16
  u16*  xcat1  = (u16*)(ws + 262400);        // [64][1024] bf16
  float* dp    = (float*)(ws + 393472);      // [64][512] f32
  float* scores = (float*)(ws + 524544);     // [16384] f32
  float* hl1f  = (float*)(ws + 590080);      // [64][512] f32
  u16*  svec   = (u16*)(ws + 721152);        // [64][512] bf16

  // c0 element offsets (dtype-independent): layer 1 at +32768 elements
  k_flag<<<1, 64, 0, stream>>>((const u32*)lneg, flag);

  k_prep<false><<<128, 256, 0, stream>>>(flag, tok, h0, emb, lneg, lneb, benc, Wdec, bdec, xcat, xcat1, dp);
  k_prep<true ><<<128, 256, 0, stream>>>(flag, tok, h0, emb, lneg, lneb, benc, Wdec, bdec, xcat, xcat1, dp);

  k_scores<false><<<256, 512, 0, stream>>>(flag, enc, Wenc, dp, lnag, lnab, vat, mask, scores);
  k_scores<true ><<<256, 512, 0, stream>>>(flag, enc, Wenc, dp, lnag, lnab, vat, mask, scores);

  k_softmax_ctx<false><<<256, 256, 0, stream>>>(flag, scores, enc, xcat, d_out);
  k_softmax_ctx<true ><<<256, 256, 0, stream>>>(flag, scores, enc, xcat, d_out);

  k_lstm<false><<<32, 512, 0, stream>>>(flag, xcat, 2048, Wih0, 1536, Whh0, 512, bih0, bhh0,
                                        c0v, d_out, OFF_H, OFF_C, xcat1, (float*)nullptr);
  k_lstm<true ><<<32, 512, 0, stream>>>(flag, xcat, 2048, Wih0, 1536, Whh0, 512, bih0, bhh0,
                                        c0v, d_out, OFF_H, OFF_C, xcat1, (float*)nullptr);

  // layer 1: cprev advanced by 32768 elements (dtype-dependent pointer) — pass
  // base and offset via h_off/c_off instead: use separate void* computed per dtype
  // inside the kernel is not possible; instead exploit that cprev is only read
  // via ld1 with element index — so pass base and add offset in index:
  k_lstm<false><<<32, 512, 0, stream>>>(flag, xcat1, 1024, Wih1, 512, Whh1, 512, bih1, bhh1,
                                        (const void*)((const char*)c0v + 32768 * 2), d_out,
                                        OFF_H + 32768, OFF_C + 32768,
                                        (u16*)nullptr, hl1f);
  k_lstm<true ><<<32, 512, 0, stream>>>(flag, xcat1, 1024, Wih1, 512, Whh1, 512, bih1, bhh1,
                                        (const void*)((const char*)c0v + 32768 * 4), d_out,
                                        OFF_H + 32768, OFF_C + 32768,
                                        (u16*)nullptr, hl1f);

  k_svec<false><<<64, 256, 0, stream>>>(flag, hl1f, xcat, Wctx, bctx, lnlg, lnlb, svec);
  k_svec<true ><<<64, 256, 0, stream>>>(flag, hl1f, xcat, Wctx, bctx, lnlg, lnlb, svec);

  k_logits<false><<<250, 256, 0, stream>>>(flag, svec, Wout, bout, d_out);
  k_logits<true ><<<250, 256, 0, stream>>>(flag, svec, Wout, bout, d_out);
}

// Round 3
// 457.877 us; speedup vs baseline: 1.2029x; 1.2029x over previous
//
#include <hip/hip_runtime.h>

typedef unsigned int u32;
typedef unsigned short u16;
typedef __attribute__((ext_vector_type(8))) short short8;
typedef __attribute__((ext_vector_type(4))) float f32x4;

__device__ __forceinline__ float bf2f(u16 u) {
  union { u32 i; float f; } v; v.i = ((u32)u) << 16; return v.f;
}
__device__ __forceinline__ u16 f2bf(float f) {
  union { float f; u32 i; } v; v.f = f;
  u32 u = v.i;
  u += 0x7FFFu + ((u >> 16) & 1u);
  return (u16)(u >> 16);
}
__device__ __forceinline__ float tanh_fast(float x) {
  float e = __expf(-2.f * fabsf(x));
  float r = (1.f - e) / (1.f + e);
  return x < 0.f ? -r : r;
}
__device__ __forceinline__ float sigmoid_fast(float x) {
  return 1.f / (1.f + __expf(-x));
}
template<bool F32>
__device__ __forceinline__ float ld1(const void* p, size_t i) {
  return F32 ? ((const float*)p)[i] : bf2f(((const u16*)p)[i]);
}
__device__ __forceinline__ void outst(void* p, size_t i, float v, int f32o) {
  if (f32o) ((float*)p)[i] = v; else ((u16*)p)[i] = f2bf(v);
}

#define OFF_H    2048000
#define OFF_C    2113536
#define OFF_ATTN 2179072

// arena (f32) element offsets
#define A_LNAG 0
#define A_LNAB 512
#define A_VAT  1024
#define A_BENC 1536
#define A_BDEC 2048
#define A_BIH0 2560
#define A_BHH0 4608
#define A_BIH1 6656
#define A_BHH1 8704
#define A_LNLG 10752
#define A_LNLB 11264
#define A_BCTX 11776
#define A_BOUT 12288
#define A_TOTAL 44288

struct SrcPtrs {
  const void *h0, *c0, *emb, *lneg, *lneb, *Wenc, *benc, *Wdec, *bdec, *vat,
             *lnag, *lnab, *bih0, *bhh0, *bih1, *bhh1, *lnlg, *lnlb, *Wctx,
             *bctx, *bout;
  const int *tok;
};

// ---------------------------------------------------------------------------
__global__ void k_flag(const u32* __restrict__ lneg, int* __restrict__ flag) {
  if (threadIdx.x == 0) flag[0] = (lneg[0] == 0x3F800000u) ? 1 : 0;
}

// ---------------------------------------------------------------------------
// K1 (dual-dtype): emb-LN -> xcat[:,0:512]; h0l0 -> xcat[:,1536:]; h0l1 ->
// xcat1[:,512:]+h1bf; c0 -> c0f; Wenc/Wdec/Wctx -> bf16; smalls -> f32 arena
// grid 460 x 256
// ---------------------------------------------------------------------------
template<bool F32>
__device__ __forceinline__ void convblk(const void* src, u16* dst, size_t base) {
  size_t i0 = base + (size_t)threadIdx.x * 16;
  if (F32) {
    const float* s = (const float*)src + i0;
    float4 a = *(const float4*)s, b = *(const float4*)(s + 4);
    float4 c = *(const float4*)(s + 8), d = *(const float4*)(s + 12);
    short8 v0, v1;
    v0[0]=(short)f2bf(a.x); v0[1]=(short)f2bf(a.y); v0[2]=(short)f2bf(a.z); v0[3]=(short)f2bf(a.w);
    v0[4]=(short)f2bf(b.x); v0[5]=(short)f2bf(b.y); v0[6]=(short)f2bf(b.z); v0[7]=(short)f2bf(b.w);
    v1[0]=(short)f2bf(c.x); v1[1]=(short)f2bf(c.y); v1[2]=(short)f2bf(c.z); v1[3]=(short)f2bf(c.w);
    v1[4]=(short)f2bf(d.x); v1[5]=(short)f2bf(d.y); v1[6]=(short)f2bf(d.z); v1[7]=(short)f2bf(d.w);
    *(short8*)(dst + i0) = v0; *(short8*)(dst + i0 + 8) = v1;
  } else {
    const uint4* s = (const uint4*)((const u16*)src + i0);
    uint4 a = s[0], b = s[1];
    *(uint4*)(dst + i0) = a; *((uint4*)(dst + i0) + 1) = b;
  }
}

template<bool F32>
__global__ __launch_bounds__(256) void k_conv(
    const int* __restrict__ flagp, SrcPtrs P,
    u16* __restrict__ xcat, u16* __restrict__ xcat1, u16* __restrict__ h1bf,
    float* __restrict__ c0f, float* __restrict__ arena,
    u16* __restrict__ Wencbf, u16* __restrict__ Wdecbf, u16* __restrict__ Wctxbf)
{
  if (flagp[0] != (F32 ? 1 : 0)) return;
  __shared__ float red[8];
  const int t = threadIdx.x;
  const int blk = blockIdx.x;
  if (blk < 64) {
    const int b = blk;
    const int tk = P.tok[b];
    float e0 = ld1<F32>(P.emb, (size_t)tk * 512 + t);
    float e1 = ld1<F32>(P.emb, (size_t)tk * 512 + t + 256);
    float s = e0 + e1, ss = e0 * e0 + e1 * e1;
    #pragma unroll
    for (int o = 1; o < 64; o <<= 1) { s += __shfl_xor(s, o, 64); ss += __shfl_xor(ss, o, 64); }
    if ((t & 63) == 0) { red[t >> 6] = s; red[4 + (t >> 6)] = ss; }
    __syncthreads();
    s = red[0] + red[1] + red[2] + red[3];
    ss = red[4] + red[5] + red[6] + red[7];
    const float mean = s * (1.f / 512.f);
    const float rstd = rsqrtf(fmaxf(ss * (1.f / 512.f) - mean * mean, 0.f) + 1e-5f);
    xcat[b*2048 + t]       = f2bf((e0 - mean) * rstd * ld1<F32>(P.lneg, t) + ld1<F32>(P.lneb, t));
    xcat[b*2048 + t + 256] = f2bf((e1 - mean) * rstd * ld1<F32>(P.lneg, t + 256) + ld1<F32>(P.lneb, t + 256));
    xcat[b*2048 + 1536 + t]       = f2bf(ld1<F32>(P.h0, (size_t)b * 512 + t));
    xcat[b*2048 + 1536 + t + 256] = f2bf(ld1<F32>(P.h0, (size_t)b * 512 + t + 256));
  } else if (blk < 128) {
    const int b = blk - 64;
    for (int j = t; j < 512; j += 256) {
      float h1 = ld1<F32>(P.h0, 32768 + (size_t)b * 512 + j);
      xcat1[b*1024 + 512 + j] = f2bf(h1);
      h1bf[b*512 + j] = f2bf(h1);
      c0f[b*512 + j]         = ld1<F32>(P.c0, (size_t)b * 512 + j);
      c0f[32768 + b*512 + j] = ld1<F32>(P.c0, 32768 + (size_t)b * 512 + j);
    }
  } else if (blk < 256) {
    convblk<F32>(P.Wenc, Wencbf, (size_t)(blk - 128) * 4096);
  } else if (blk < 320) {
    convblk<F32>(P.Wdec, Wdecbf, (size_t)(blk - 256) * 4096);
  } else if (blk < 448) {
    convblk<F32>(P.Wctx, Wctxbf, (size_t)(blk - 320) * 4096);
  } else {
    int base = (blk - 448) * 4096;
    for (int i = t; i < 4096; i += 256) {
      int v = base + i;
      if (v >= A_TOTAL) break;
      const void* s; int off;
      if      (v < 512)   { s = P.lnag; off = v; }
      else if (v < 1024)  { s = P.lnab; off = v - 512; }
      else if (v < 1536)  { s = P.vat;  off = v - 1024; }
      else if (v < 2048)  { s = P.benc; off = v - 1536; }
      else if (v < 2560)  { s = P.bdec; off = v - 2048; }
      else if (v < 4608)  { s = P.bih0; off = v - 2560; }
      else if (v < 6656)  { s = P.bhh0; off = v - 4608; }
      else if (v < 8704)  { s = P.bih1; off = v - 6656; }
      else if (v < 10752) { s = P.bhh1; off = v - 8704; }
      else if (v < 11264) { s = P.lnlg; off = v - 10752; }
      else if (v < 11776) { s = P.lnlb; off = v - 11264; }
      else if (v < 12288) { s = P.bctx; off = v - 11776; }
      else                { s = P.bout; off = v - 12288; }
      arena[v] = ld1<F32>(s, off);
    }
  }
}

// ---------------------------------------------------------------------------
// K2: scores = mask( tanh(LN(enc@Wenc^T + h1@Wdec^T + benc + bdec)) . v_att )
// grid 256 x 512; reg-pipelined staging; dp via MFMA preamble; reg-LN epilogue
// ---------------------------------------------------------------------------
__global__ __launch_bounds__(512) void k_scores(
    const int* __restrict__ flagp,
    const void* __restrict__ enc, const u16* __restrict__ Wencbf,
    const u16* __restrict__ Wdecbf, const u16* __restrict__ h1bf,
    const float* __restrict__ arena, const int* __restrict__ mask,
    float* __restrict__ scores)
{
  const int f32w = flagp[0];
  __shared__ __align__(16) char sm[36864];  // A 4K @0, B 32K @4096
  const int t = threadIdx.x, wave = t >> 6, lane = t & 63;
  const int q = lane >> 4, r15 = lane & 15;
  const int m0 = blockIdx.x * 64, b = m0 >> 8, n0 = wave * 64;

  // dec_proj preamble (rows of D all identical since A-rows replicated)
  f32x4 dpacc[4] = {};
  #pragma unroll
  for (int kc2 = 0; kc2 < 16; kc2++) {
    short8 haf = *(const short8*)(h1bf + b * 512 + kc2 * 32 + q * 8);
    #pragma unroll
    for (int ni = 0; ni < 4; ni++) {
      short8 wf = *(const short8*)(Wdecbf + (size_t)(n0 + ni*16 + r15) * 512 + kc2 * 32 + q * 8);
      dpacc[ni] = __builtin_amdgcn_mfma_f32_16x16x32_bf16(haf, wf, dpacc[ni], 0, 0, 0);
    }
  }
  float dpv[4];
  #pragma unroll
  for (int ni = 0; ni < 4; ni++) {
    int col = n0 + ni*16 + r15;
    dpv[ni] = dpacc[ni][0] + arena[A_BENC + col] + arena[A_BDEC + col];
  }

  uint4 rB[4]; float4 rA0, rA1; uint4 rAc;
  const int arow = t >> 2, acq = t & 3;
  auto issue = [&](int kc) {
    #pragma unroll
    for (int rr = 0; rr < 4; rr++) {
      int c2 = rr * 512 + t;
      int col = c2 >> 2, cq = c2 & 3;
      rB[rr] = *(const uint4*)(Wencbf + (size_t)col * 1024 + kc + cq * 8);
    }
    if (t < 256) {
      size_t off = (size_t)(m0 + arow) * 1024 + kc + acq * 8;
      if (f32w) {
        const float* p = (const float*)enc + off;
        rA0 = *(const float4*)p; rA1 = *(const float4*)(p + 4);
      } else {
        rAc = *(const uint4*)((const u16*)enc + off);
      }
    }
  };
  issue(0);
  f32x4 acc[4][4] = {};
  for (int kc = 0; kc < 1024; kc += 32) {
    #pragma unroll
    for (int rr = 0; rr < 4; rr++) {
      int c2 = rr * 512 + t;
      int col = c2 >> 2, cq = c2 & 3;
      *(uint4*)(sm + 4096 + (cq * 512 + col) * 16) = rB[rr];
    }
    if (t < 256) {
      if (f32w) {
        short8 v;
        v[0]=(short)f2bf(rA0.x); v[1]=(short)f2bf(rA0.y); v[2]=(short)f2bf(rA0.z); v[3]=(short)f2bf(rA0.w);
        v[4]=(short)f2bf(rA1.x); v[5]=(short)f2bf(rA1.y); v[6]=(short)f2bf(rA1.z); v[7]=(short)f2bf(rA1.w);
        *(short8*)(sm + (acq * 64 + arow) * 16) = v;
      } else {
        *(uint4*)(sm + (acq * 64 + arow) * 16) = rAc;
      }
    }
    __syncthreads();
    if (kc + 32 < 1024) issue(kc + 32);
    short8 af[4], bfr[4];
    #pragma unroll
    for (int mi = 0; mi < 4; mi++)
      af[mi] = *(const short8*)(sm + (q * 64 + mi * 16 + r15) * 16);
    #pragma unroll
    for (int ni = 0; ni < 4; ni++)
      bfr[ni] = *(const short8*)(sm + 4096 + (q * 512 + n0 + ni * 16 + r15) * 16);
    #pragma unroll
    for (int mi = 0; mi < 4; mi++)
      #pragma unroll
      for (int ni = 0; ni < 4; ni++)
        acc[mi][ni] = __builtin_amdgcn_mfma_f32_16x16x32_bf16(af[mi], bfr[ni], acc[mi][ni], 0, 0, 0);
    __syncthreads();
  }

  // register-space LN + tanh + dot(v_att)
  float* ps    = (float*)sm;            // [8][64]
  float* pq    = (float*)(sm + 2048);   // [8][64]
  float* mean_ = (float*)(sm + 4096);   // [64]
  float* rstd_ = (float*)(sm + 4352);   // [64]
  #pragma unroll
  for (int mi = 0; mi < 4; mi++)
    #pragma unroll
    for (int r = 0; r < 4; r++) {
      float s = 0.f, sq = 0.f;
      #pragma unroll
      for (int ni = 0; ni < 4; ni++) {
        float x = acc[mi][ni][r] + dpv[ni];
        s += x; sq += x * x;
      }
      #pragma unroll
      for (int o = 1; o < 16; o <<= 1) { s += __shfl_xor(s, o, 64); sq += __shfl_xor(sq, o, 64); }
      if (r15 == 0) { int row = mi*16 + q*4 + r; ps[wave*64 + row] = s; pq[wave*64 + row] = sq; }
    }
  __syncthreads();
  if (t < 64) {
    float s = 0.f, sq = 0.f;
    #pragma unroll
    for (int w = 0; w < 8; w++) { s += ps[w*64 + t]; sq += pq[w*64 + t]; }
    float mn = s * (1.f / 512.f);
    mean_[t] = mn;
    rstd_[t] = rsqrtf(fmaxf(sq * (1.f / 512.f) - mn * mn, 0.f) + 1e-5f);
  }
  __syncthreads();
  float g4[4], b4[4], v4[4];
  #pragma unroll
  for (int ni = 0; ni < 4; ni++) {
    int col = n0 + ni*16 + r15;
    g4[ni] = arena[A_LNAG + col]; b4[ni] = arena[A_LNAB + col]; v4[ni] = arena[A_VAT + col];
  }
  #pragma unroll
  for (int mi = 0; mi < 4; mi++)
    #pragma unroll
    for (int r = 0; r < 4; r++) {
      int row = mi*16 + q*4 + r;
      float mn = mean_[row], rs = rstd_[row];
      float s = 0.f;
      #pragma unroll
      for (int ni = 0; ni < 4; ni++) {
        float x = acc[mi][ni][r] + dpv[ni];
        float y = (x - mn) * rs * g4[ni] + b4[ni];
        s += tanh_fast(y) * v4[ni];
      }
      #pragma unroll
      for (int o = 1; o < 16; o <<= 1) s += __shfl_xor(s, o, 64);
      if (r15 == 0) ps[wave*64 + row] = s;
    }
  __syncthreads();
  if (t < 64) {
    float sc = 0.f;
    #pragma unroll
    for (int w = 0; w < 8; w++) sc += ps[w*64 + t];
    int s_ = (m0 & 255) + t;
    scores[m0 + t] = mask[b*256 + s_] ? sc : -__builtin_inff();
  }
}

// ---------------------------------------------------------------------------
// K3: softmax over S + context; grid 256 (b, kq) x 256
// ---------------------------------------------------------------------------
__global__ __launch_bounds__(256) void k_softmax_ctx(
    const int* __restrict__ flagp,
    const float* __restrict__ scores, const void* __restrict__ enc,
    u16* __restrict__ xcat, void* __restrict__ out)
{
  const int f32w = flagp[0];
  __shared__ float aw[256];
  __shared__ float red[8];
  __shared__ float px[512];
  const int t = threadIdx.x;
  const int b = blockIdx.x >> 2, kq = blockIdx.x & 3;
  float sv = scores[b * 256 + t];
  float mx = sv;
  #pragma unroll
  for (int o = 1; o < 64; o <<= 1) mx = fmaxf(mx, __shfl_xor(mx, o, 64));
  if ((t & 63) == 0) red[t >> 6] = mx;
  __syncthreads();
  mx = fmaxf(fmaxf(red[0], red[1]), fmaxf(red[2], red[3]));
  float e = __expf(sv - mx);
  float s = e;
  #pragma unroll
  for (int o = 1; o < 64; o <<= 1) s += __shfl_xor(s, o, 64);
  if ((t & 63) == 0) red[4 + (t >> 6)] = s;
  __syncthreads();
  s = red[4] + red[5] + red[6] + red[7];
  float w = e / s;
  aw[t] = w;
  if (kq == 0) outst(out, OFF_ATTN + b * 256 + t, w, f32w);
  __syncthreads();
  const int kk = t & 127, sg = t >> 7;
  float a0 = 0.f, a1 = 0.f;
  if (f32w) {
    const float* p = (const float*)enc + (size_t)b * 262144 + kq * 256 + kk * 2;
    #pragma unroll 4
    for (int i = 0; i < 128; i++) {
      int si = i * 2 + sg;
      float2 v = *(const float2*)(p + (size_t)si * 1024);
      a0 += aw[si] * v.x; a1 += aw[si] * v.y;
    }
  } else {
    const u16* p = (const u16*)enc + (size_t)b * 262144 + kq * 256 + kk * 2;
    #pragma unroll 4
    for (int i = 0; i < 128; i++) {
      int si = i * 2 + sg;
      u32 u = *(const u32*)(p + (size_t)si * 1024);
      a0 += aw[si] * bf2f((u16)(u & 0xffff)); a1 += aw[si] * bf2f((u16)(u >> 16));
    }
  }
  px[sg * 256 + kk * 2]     = a0;
  px[sg * 256 + kk * 2 + 1] = a1;
  __syncthreads();
  float cv = px[t] + px[256 + t];
  xcat[b * 2048 + 512 + kq * 256 + t] = f2bf(cv);
}

// ---------------------------------------------------------------------------
// K4: LSTM layer; grid 128 (4 cells each) x 512; split-K over 8 waves
// ---------------------------------------------------------------------------
__global__ __launch_bounds__(512) void k_lstm(
    const int* __restrict__ flagp,
    const u16* __restrict__ x, int K,
    const void* __restrict__ Wa, int Ka,
    const void* __restrict__ Wb, int Kb,
    int boff_ih, int boff_hh,
    const float* __restrict__ arena, const float* __restrict__ c0f, int coff,
    void* __restrict__ out, size_t h_off, size_t c_off,
    u16* __restrict__ aux_bf, float* __restrict__ aux_f)
{
  const int f32w = flagp[0];
  __shared__ __align__(16) char sm[40960];
  const int t = threadIdx.x, wave = t >> 6, lane = t & 63;
  const int q = lane >> 4, r15 = lane & 15;
  const int jt = blockIdx.x;
  const int kslice = K >> 3, ksteps = kslice >> 5;
  const int k0 = wave * kslice;
  const void* W; int Kw, koff;
  if (k0 < Ka) { W = Wa; Kw = Ka; koff = k0; }
  else         { W = Wb; Kw = Kb; koff = k0 - Ka; }
  char* slab = sm + wave * 5120;
  const int bc = lane >> 2, bcq = lane & 3;          // B chunk: tile col, k-quarter
  const int wrow = (bc >> 2) * 512 + jt * 4 + (bc & 3);
  f32x4 acc4[4] = {};

  for (int st = 0; st < ksteps; ++st) {
    const int kA = k0 + st * 32;
    const int kB = koff + st * 32;
    #pragma unroll
    for (int i = 0; i < 4; i++) {
      int id = i * 64 + lane;
      int row = id >> 2, cq = id & 3;
      *(uint4*)(slab + (cq * 64 + row) * 16) = *(const uint4*)(x + (size_t)row * K + kA + cq * 8);
    }
    {
      size_t wi = (size_t)wrow * Kw + kB + bcq * 8;
      short8 bv;
      if (f32w) {
        const float* wp = (const float*)W + wi;
        float4 a = *(const float4*)wp, b = *(const float4*)(wp + 4);
        bv[0]=(short)f2bf(a.x); bv[1]=(short)f2bf(a.y); bv[2]=(short)f2bf(a.z); bv[3]=(short)f2bf(a.w);
        bv[4]=(short)f2bf(b.x); bv[5]=(short)f2bf(b.y); bv[6]=(short)f2bf(b.z); bv[7]=(short)f2bf(b.w);
      } else {
        bv = *(const short8*)((const u16*)W + wi);
      }
      *(short8*)(slab + 4096 + (bcq * 16 + bc) * 16) = bv;
    }
    short8 af[4];
    #pragma unroll
    for (int mi = 0; mi < 4; mi++)
      af[mi] = *(const short8*)(slab + (q * 64 + mi * 16 + r15) * 16);
    short8 bfrg = *(const short8*)(slab + 4096 + (q * 16 + r15) * 16);
    #pragma unroll
    for (int mi = 0; mi < 4; mi++)
      acc4[mi] = __builtin_amdgcn_mfma_f32_16x16x32_bf16(af[mi], bfrg, acc4[mi], 0, 0, 0);
  }
  __syncthreads();
  float* part = (float*)sm;  // [8][64][16]
  #pragma unroll
  for (int mi = 0; mi < 4; mi++)
    #pragma unroll
    for (int r = 0; r < 4; r++)
      part[wave * 1024 + (mi * 16 + q * 4 + r) * 16 + r15] = acc4[mi][r];
  __syncthreads();
  if (t < 256) {
    const int b_ = t >> 2, cl = t & 3;
    const int jg = jt * 4 + cl;
    float g4[4];
    #pragma unroll
    for (int g = 0; g < 4; g++) {
      float v = 0.f;
      #pragma unroll
      for (int w = 0; w < 8; w++) v += part[w * 1024 + b_ * 16 + g * 4 + cl];
      g4[g] = v + arena[boff_ih + g * 512 + jg] + arena[boff_hh + g * 512 + jg];
    }
    float i_ = sigmoid_fast(g4[0]), f_ = sigmoid_fast(g4[1]), o_ = sigmoid_fast(g4[3]);
    float gg = tanh_fast(g4[2]);
    float c_ = f_ * c0f[coff + b_ * 512 + jg] + i_ * gg;
    float h_ = o_ * tanh_fast(c_);
    outst(out, h_off + b_ * 512 + jg, h_, f32w);
    outst(out, c_off + b_ * 512 + jg, c_, f32w);
    if (aux_bf) aux_bf[b_ * 1024 + jg] = f2bf(h_);
    if (aux_f)  aux_f[b_ * 512 + jg] = h_;
  }
}

// ---------------------------------------------------------------------------
// K5: svec = LN(h_l1)*g+b + context@Wctx^T + b_ctx ; grid 64 x 256
// ---------------------------------------------------------------------------
__global__ __launch_bounds__(256) void k_svec(
    const float* __restrict__ hl1f, const u16* __restrict__ xcat,
    const u16* __restrict__ Wctxbf, const float* __restrict__ arena,
    u16* __restrict__ svec)
{
  __shared__ float ctx[1024];
  __shared__ float red[8];
  const int t = threadIdx.x, b = blockIdx.x;
  for (int i = t; i < 1024; i += 256) ctx[i] = bf2f(xcat[b * 2048 + 512 + i]);
  float h0v = hl1f[b * 512 + t], h1v = hl1f[b * 512 + t + 256];
  float s = h0v + h1v, ss = h0v * h0v + h1v * h1v;
  #pragma unroll
  for (int o = 1; o < 64; o <<= 1) { s += __shfl_xor(s, o, 64); ss += __shfl_xor(ss, o, 64); }
  if ((t & 63) == 0) { red[t >> 6] = s; red[4 + (t >> 6)] = ss; }
  __syncthreads();
  s = red[0] + red[1] + red[2] + red[3];
  ss = red[4] + red[5] + red[6] + red[7];
  const float mean = s * (1.f / 512.f);
  const float rstd = rsqrtf(fmaxf(ss * (1.f / 512.f) - mean * mean, 0.f) + 1e-5f);
  for (int hh = t; hh < 512; hh += 256) {
    float hv = hl1f[b * 512 + hh];
    float lnv = (hv - mean) * rstd * arena[A_LNLG + hh] + arena[A_LNLB + hh];
    float acc = arena[A_BCTX + hh];
    #pragma unroll 4
    for (int k = 0; k < 1024; k += 8) {
      short8 wv = *(const short8*)(Wctxbf + (size_t)hh * 1024 + k);
      #pragma unroll
      for (int i = 0; i < 8; i++) acc += ctx[k + i] * bf2f((u16)wv[i]);
    }
    svec[b * 512 + hh] = f2bf(lnv + acc);
  }
}

// ---------------------------------------------------------------------------
// K6: logits = svec @ Wout^T + b_out ; grid 250 x 256; coalesced B staging
// ---------------------------------------------------------------------------
__global__ __launch_bounds__(256) void k_logits(
    const int* __restrict__ flagp,
    const u16* __restrict__ svec, const void* __restrict__ Wout,
    const float* __restrict__ arena, void* __restrict__ out)
{
  const int f32w = flagp[0];
  __shared__ __align__(16) char sm[8192];  // B tile [4][128][16B]
  const int t = threadIdx.x, wave = t >> 6, lane = t & 63;
  const int q = lane >> 4, r15 = lane & 15;
  const int nb = blockIdx.x * 128;
  float4 ra[2], rb[2]; uint4 rc[2];
  auto issue = [&](int kc) {
    #pragma unroll
    for (int i = 0; i < 2; i++) {
      int c = i * 256 + t;
      int row = c >> 2, cq = c & 3;
      size_t off = (size_t)(nb + row) * 512 + kc * 32 + cq * 8;
      if (f32w) {
        const float* p = (const float*)Wout + off;
        ra[i] = *(const float4*)p; rb[i] = *(const float4*)(p + 4);
      } else {
        rc[i] = *(const uint4*)((const u16*)Wout + off);
      }
    }
  };
  issue(0);
  f32x4 acc[4][2] = {};
  for (int kc = 0; kc < 16; kc++) {
    #pragma unroll
    for (int i = 0; i < 2; i++) {
      int c = i * 256 + t;
      int row = c >> 2, cq = c & 3;
      if (f32w) {
        short8 v;
        v[0]=(short)f2bf(ra[i].x); v[1]=(short)f2bf(ra[i].y); v[2]=(short)f2bf(ra[i].z); v[3]=(short)f2bf(ra[i].w);
        v[4]=(short)f2bf(rb[i].x); v[5]=(short)f2bf(rb[i].y); v[6]=(short)f2bf(rb[i].z); v[7]=(short)f2bf(rb[i].w);
        *(short8*)(sm + (cq * 128 + row) * 16) = v;
      } else {
        *(uint4*)(sm + (cq * 128 + row) * 16) = rc[i];
      }
    }
    __syncthreads();
    if (kc + 1 < 16) issue(kc + 1);
    short8 af[4], bfr[2];
    #pragma unroll
    for (int mi = 0; mi < 4; mi++)
      af[mi] = *(const short8*)(svec + (size_t)(mi * 16 + r15) * 512 + kc * 32 + q * 8);
    #pragma unroll
    for (int ni = 0; ni < 2; ni++)
      bfr[ni] = *(const short8*)(sm + (q * 128 + wave * 32 + ni * 16 + r15) * 16);
    #pragma unroll
    for (int mi = 0; mi < 4; mi++)
      #pragma unroll
      for (int ni = 0; ni < 2; ni++)
        acc[mi][ni] = __builtin_amdgcn_mfma_f32_16x16x32_bf16(af[mi], bfr[ni], acc[mi][ni], 0, 0, 0);
    __syncthreads();
  }
  #pragma unroll
  for (int ni = 0; ni < 2; ni++) {
    int col = nb + wave * 32 + ni * 16 + r15;
    float bo = arena[A_BOUT + col];
    #pragma unroll
    for (int mi = 0; mi < 4; mi++)
      #pragma unroll
      for (int r = 0; r < 4; r++) {
        int brow = mi * 16 + q * 4 + r;
        outst(out, (size_t)brow * 32000 + col, acc[mi][ni][r] + bo, f32w);
      }
  }
}

// ---------------------------------------------------------------------------
extern "C" void kernel_launch(void* const* d_in, const int* in_sizes, int n_in,
                              void* d_out, int out_size, void* d_ws, size_t ws_size,
                              hipStream_t stream)
{
  SrcPtrs P;
  P.tok  = (const int*)d_in[0];
  P.h0   = d_in[1];  P.c0   = d_in[2];
  const void* enc = d_in[3];
  const int* mask = (const int*)d_in[4];
  P.emb  = d_in[5]; P.lneg = d_in[6]; P.lneb = d_in[7];
  P.Wenc = d_in[8]; P.benc = d_in[9]; P.Wdec = d_in[10]; P.bdec = d_in[11];
  P.vat  = d_in[12]; P.lnag = d_in[13]; P.lnab = d_in[14];
  P.bih0 = d_in[17]; P.bhh0 = d_in[18];
  P.bih1 = d_in[21]; P.bhh1 = d_in[22];
  P.lnlg = d_in[23]; P.lnlb = d_in[24];
  P.Wctx = d_in[25]; P.bctx = d_in[26];
  const void* Wout = d_in[27];
  P.bout = d_in[28];
  const void* Wih0 = d_in[15];
  const void* Whh0 = d_in[16];
  const void* Wih1 = d_in[19];
  const void* Whh1 = d_in[20];

  char* ws = (char*)d_ws;
  int*   flag    = (int*)(ws + 0);
  float* arena   = (float*)(ws + 256);        // 177152 B
  u16*   Wencbf  = (u16*)(ws + 177664);       // 1048576
  u16*   Wdecbf  = (u16*)(ws + 1226240);      // 524288
  u16*   Wctxbf  = (u16*)(ws + 1750528);      // 1048576
  u16*   xcat    = (u16*)(ws + 2799104);      // 262144
  u16*   xcat1   = (u16*)(ws + 3061248);      // 131072
  u16*   h1bf    = (u16*)(ws + 3192320);      // 65536
  float* c0f     = (float*)(ws + 3257856);    // 262144
  float* scores  = (float*)(ws + 3520000);    // 65536
  float* hl1f    = (float*)(ws + 3585536);    // 131072
  u16*   svec    = (u16*)(ws + 3716608);      // 65536

  k_flag<<<1, 64, 0, stream>>>((const u32*)P.lneg, flag);
  k_conv<false><<<460, 256, 0, stream>>>(flag, P, xcat, xcat1, h1bf, c0f, arena, Wencbf, Wdecbf, Wctxbf);
  k_conv<true ><<<460, 256, 0, stream>>>(flag, P, xcat, xcat1, h1bf, c0f, arena, Wencbf, Wdecbf, Wctxbf);
  k_scores<<<256, 512, 0, stream>>>(flag, enc, Wencbf, Wdecbf, h1bf, arena, mask, scores);
  k_softmax_ctx<<<256, 256, 0, stream>>>(flag, scores, enc, xcat, d_out);
  k_lstm<<<128, 512, 0, stream>>>(flag, xcat, 2048, Wih0, 1536, Whh0, 512,
                                  A_BIH0, A_BHH0, arena, c0f, 0,
                                  d_out, OFF_H, OFF_C, xcat1, (float*)nullptr);
  k_lstm<<<128, 512, 0, stream>>>(flag, xcat1, 1024, Wih1, 512, Whh1, 512,
                                  A_BIH1, A_BHH1, arena, c0f, 32768,
                                  d_out, OFF_H + 32768, OFF_C + 32768,
                                  (u16*)nullptr, hl1f);
  k_svec<<<64, 256, 0, stream>>>(hl1f, xcat, Wctxbf, arena, svec);
  k_logits<<<250, 256, 0, stream>>>(flag, svec, Wout, arena, d_out);
}